// Round 11
// baseline (123.701 us; speedup 1.0000x reference)
//
#include <hip/hip_runtime.h>
#include <hip/hip_bf16.h>

typedef __bf16 bf16x8 __attribute__((ext_vector_type(8)));
typedef __bf16 bf16x4 __attribute__((ext_vector_type(4)));
typedef float  f32x4  __attribute__((ext_vector_type(4)));
typedef float  flt4v  __attribute__((ext_vector_type(4)));
typedef int    int4v  __attribute__((ext_vector_type(4)));

#define ALPHA 0.2f
#define LOG2E 1.44269504089f
// B=8, N=2048, D=128. Inputs: h,W,a f32; adj int32. Output f32.

// spread 16 bits so bit m -> bit 4m (bit-plane -> chunk-word transpose)
__device__ __forceinline__ unsigned long long spread4(unsigned long long x) {
    x &= 0xFFFFull;
    x = (x | (x << 24)) & 0x000000FF000000FFull;
    x = (x | (x << 12)) & 0x000F000F000F000Full;
    x = (x | (x << 6))  & 0x0303030303030303ull;
    x = (x | (x << 3))  & 0x1111111111111111ull;
    return x;
}

// Fused prep kernel: blocks [0,2048) pack adj -> bitmask; blocks [2048,2304) do
// Wh = bf16(h)@bf16(W) (MFMA) + scores. Independent work, overlapped in one launch.
// Scores stored PRE-SCALED by log2(e) so attn uses exp2f directly.
__global__ __launch_bounds__(256) void gat_prep(
    const int*   __restrict__ adj,           // [8*2048*2048]
    const float* __restrict__ h,             // [8][2048][128] f32
    const float* __restrict__ W,             // [128][128] f32
    const float* __restrict__ a,             // [256] f32
    unsigned long long* __restrict__ msk,    // [8*2048*32]
    __bf16* __restrict__ wht,                // [8][128][2048] bf16
    float* __restrict__ ssrc,                // [8*2048] (x log2e)
    float* __restrict__ sdst)                // [8*2048] (x log2e)
{
    __shared__ __bf16 Wt[128][136];       // used by wh-part only
    __shared__ float wvs[128], wvd[128];
    const int tid = threadIdx.x;

    if (blockIdx.x < 2048) {
        // ---- pack part: wave handles 16 groups of 256 ints (16 B/lane loads) ----
        const int lane = tid & 63;
        const int wid  = (blockIdx.x * 256 + tid) >> 6;   // 8192 waves
        const int g0   = wid * 16;
        #pragma unroll 4
        for (int it = 0; it < 16; ++it) {
            const int g = g0 + it;
            int4v v = *reinterpret_cast<const int4v*>(adj + (size_t)g * 256 + lane * 4);
            unsigned long long b0 = __ballot(v[0] != 0);
            unsigned long long b1 = __ballot(v[1] != 0);
            unsigned long long b2 = __ballot(v[2] != 0);
            unsigned long long b3 = __ballot(v[3] != 0);
            if (lane < 4) {
                const int k = lane;
                unsigned long long w =  spread4(b0 >> (16 * k))
                                     | (spread4(b1 >> (16 * k)) << 1)
                                     | (spread4(b2 >> (16 * k)) << 2)
                                     | (spread4(b3 >> (16 * k)) << 3);
                msk[(size_t)g * 4 + k] = w;
            }
        }
        return;
    }

    // ---- wh part ----
    const int bidw = blockIdx.x - 2048;      // 0..255
    if (tid < 128) {
        float s0 = 0.f, s1 = 0.f;
        const float* wr = W + tid * 128;
        #pragma unroll 4
        for (int e = 0; e < 128; ++e) {
            float w = wr[e];
            s0 += w * a[e];
            s1 += w * a[128 + e];
        }
        wvs[tid] = s0; wvd[tid] = s1;
    }
    #pragma unroll
    for (int it = 0; it < 8; ++it) {
        int o = (it * 256 + tid) * 8;
        flt4v v0 = *reinterpret_cast<const flt4v*>(W + o);
        flt4v v1 = *reinterpret_cast<const flt4v*>(W + o + 4);
        int d = o >> 7, e = o & 127;
        #pragma unroll
        for (int j = 0; j < 4; ++j) {
            Wt[e + j][d]     = (__bf16)v0[j];
            Wt[e + 4 + j][d] = (__bf16)v1[j];
        }
    }
    __syncthreads();
    const int wave = tid >> 6, lane = tid & 63;
    const int lr = lane & 15, lg = lane >> 4;
    const int row0 = bidw * 64 + wave * 16;
    f32x4 acc[8];
    #pragma unroll
    for (int ct = 0; ct < 8; ++ct) acc[ct] = (f32x4){0.f, 0.f, 0.f, 0.f};
    #pragma unroll
    for (int kk = 0; kk < 4; ++kk) {
        const float* hp = h + (size_t)(row0 + lr) * 128 + kk * 32 + lg * 8;
        flt4v h0 = *reinterpret_cast<const flt4v*>(hp);
        flt4v h1 = *reinterpret_cast<const flt4v*>(hp + 4);
        bf16x8 af;
        #pragma unroll
        for (int j = 0; j < 4; ++j) { af[j] = (__bf16)h0[j]; af[4 + j] = (__bf16)h1[j]; }
        #pragma unroll
        for (int ct = 0; ct < 8; ++ct) {
            bf16x8 bf_ = *reinterpret_cast<const bf16x8*>(&Wt[ct * 16 + lr][kk * 32 + lg * 8]);
            acc[ct] = __builtin_amdgcn_mfma_f32_16x16x32_bf16(af, bf_, acc[ct], 0, 0, 0);
        }
    }
    const int b  = row0 >> 11;
    const int n0 = row0 & 2047;
    __bf16* wb = wht + (size_t)b * 128 * 2048;
    #pragma unroll
    for (int ct = 0; ct < 8; ++ct) {
        bf16x4 v;
        #pragma unroll
        for (int q = 0; q < 4; ++q) v[q] = (__bf16)acc[ct][q];
        *reinterpret_cast<bf16x4*>(wb + (ct * 16 + lr) * 2048 + n0 + lg * 4) = v;
    }
    const float* hrow = h + (size_t)(row0 + lr) * 128 + lg * 32;
    float s0 = 0.f, s1 = 0.f;
    #pragma unroll
    for (int u = 0; u < 32; u += 4) {
        flt4v hv = *reinterpret_cast<const flt4v*>(hrow + u);
        #pragma unroll
        for (int q = 0; q < 4; ++q) {
            float x = hv[q];
            s0 += x * wvs[lg * 32 + u + q];
            s1 += x * wvd[lg * 32 + u + q];
        }
    }
    s0 += __shfl_xor(s0, 16, 64); s0 += __shfl_xor(s0, 32, 64);
    s1 += __shfl_xor(s1, 16, 64); s1 += __shfl_xor(s1, 32, 64);
    if (lg == 0) {
        ssrc[row0 + lr] = s0 * LOG2E;
        sdst[row0 + lr] = s1 * LOG2E;
    }
}

// Kernel C: fused masked-softmax attention + PV. Output f32.
// Grid: 512 blocks; bid&7 = batch (XCD pinning), bid>>3 = 32-row tile.
// Block: 512 thr = 8 waves: wave>>2 = row-group (16 rows), wave&3 = j-slice.
// Masks prefetched to registers; jt loop unroll-2 for cross-tile pipelining.
__global__ __launch_bounds__(512) void gat_attn(
    const unsigned long long* __restrict__ msk, // [8*2048][32] u64 bitmask
    const __bf16* __restrict__ wht,             // [8][128][2048] bf16
    const float* __restrict__ ssrc,             // pre-scaled by log2e
    const float* __restrict__ sdst,             // pre-scaled by log2e
    float* __restrict__ out)                    // [8][2048][128] f32
{
    __shared__ float accsh[2][16][136];
    __shared__ float lsh[2][16];
    const int tid = threadIdx.x, wave = tid >> 6, lane = tid & 63;
    const int lr = lane & 15, lg = lane >> 4;
    const int g = wave >> 2, slot = wave & 3;
    const int b  = blockIdx.x & 7;              // XCD pinning
    const int i0 = (blockIdx.x >> 3) << 5;      // 32-row tile base
    const int row = i0 + g * 16 + lr;
    const float si = ssrc[b * 2048 + row];
    const unsigned long long* mrow = msk + (size_t)(b * 2048 + row) * 32;
    const float* sd = sdst + b * 2048;
    const __bf16* wb = wht + (size_t)b * 128 * 2048;

    // prefetch all 8 mask words off the critical path
    unsigned long long mwp[8];
    #pragma unroll
    for (int t = 0; t < 8; ++t) mwp[t] = mrow[slot + 4 * t];

    f32x4 acc[8];
    #pragma unroll
    for (int ct = 0; ct < 8; ++ct) acc[ct] = (f32x4){0.f, 0.f, 0.f, 0.f};
    float lpart = 0.f;

    #pragma unroll 2
    for (int t = 0; t < 8; ++t) {
        const int j0 = (slot + 4 * t) * 64;
        const unsigned long long mw = mwp[t];
        bf16x8 pf[2];
        #pragma unroll
        for (int kk = 0; kk < 2; ++kk) {
            const int jb = j0 + kk * 32 + lg * 8;
            const unsigned int m8 = (unsigned int)(mw >> (kk * 32 + lg * 8)) & 0xffu;
            #pragma unroll
            for (int v = 0; v < 2; ++v) {
                flt4v sv = *reinterpret_cast<const flt4v*>(sd + jb + v * 4);
                #pragma unroll
                for (int u = 0; u < 4; ++u) {
                    float e = si + sv[u];
                    e = fmaxf(e, ALPHA * e);        // leaky_relu (scaled domain, c>0 commutes)
                    float p = exp2f(e);
                    p = (m8 & (1u << (v * 4 + u))) ? p : 0.f;
                    __bf16 pb = (__bf16)p;
                    lpart += (float)pb;             // denom matches bf16 numerator
                    pf[kk][v * 4 + u] = pb;
                }
            }
        }
        #pragma unroll
        for (int kk = 0; kk < 2; ++kk) {
            const int jb = j0 + kk * 32 + lg * 8;
            #pragma unroll
            for (int ct = 0; ct < 8; ++ct) {
                bf16x8 bf_ = *reinterpret_cast<const bf16x8*>(wb + (ct * 16 + lr) * 2048 + jb);
                acc[ct] = __builtin_amdgcn_mfma_f32_16x16x32_bf16(pf[kk], bf_, acc[ct], 0, 0, 0);
            }
        }
    }
    lpart += __shfl_xor(lpart, 16, 64);
    lpart += __shfl_xor(lpart, 32, 64);

    #pragma unroll
    for (int s = 0; s < 4; ++s) {
        if (slot == s) {
            if (s == 0) {
                #pragma unroll
                for (int ct = 0; ct < 8; ++ct)
                    #pragma unroll
                    for (int q = 0; q < 4; ++q)
                        accsh[g][lg * 4 + q][ct * 16 + lr] = acc[ct][q];
                if (lane < 16) lsh[g][lr] = lpart;
            } else {
                #pragma unroll
                for (int ct = 0; ct < 8; ++ct)
                    #pragma unroll
                    for (int q = 0; q < 4; ++q)
                        accsh[g][lg * 4 + q][ct * 16 + lr] += acc[ct][q];
                if (lane < 16) lsh[g][lr] += lpart;
            }
        }
        __syncthreads();
    }

    const int r  = tid >> 4;
    const int c0 = (tid & 15) * 8;
    const int rg = r >> 4, rr = r & 15;
    const float l = lsh[rg][rr];
    float* ob = out + ((size_t)b * 2048 + i0 + r) * 128 + c0;
    flt4v o0, o1;
    #pragma unroll
    for (int u = 0; u < 4; ++u) {
        o0[u] = accsh[rg][rr][c0 + u] / l;
        o1[u] = accsh[rg][rr][c0 + 4 + u] / l;
    }
    *reinterpret_cast<flt4v*>(ob)     = o0;
    *reinterpret_cast<flt4v*>(ob + 4) = o1;
}

extern "C" void kernel_launch(void* const* d_in, const int* in_sizes, int n_in,
                              void* d_out, int out_size, void* d_ws, size_t ws_size,
                              hipStream_t stream)
{
    const float* h = nullptr; const int* adj = nullptr;
    const float* W = nullptr; const float* a = nullptr;
    for (int i = 0; i < n_in; ++i) {
        switch (in_sizes[i]) {
            case 2097152:  h   = (const float*)d_in[i]; break;  // 8*2048*128
            case 33554432: adj = (const int*)d_in[i];   break;  // 8*2048*2048
            case 16384:    W   = (const float*)d_in[i]; break;  // 128*128
            case 256:      a   = (const float*)d_in[i]; break;  // 2*128
        }
    }
    if (!h || !adj || !W || !a) {
        h   = (const float*)d_in[0];
        adj = (const int*)d_in[1];
        W   = (const float*)d_in[2];
        a   = (const float*)d_in[3];
    }

    __bf16* wht = (__bf16*)d_ws;                                              // 4 MB
    unsigned long long* msk = (unsigned long long*)((char*)d_ws + (size_t)4*1024*1024); // 4 MB
    float* ssrc = (float*)((char*)d_ws + (size_t)8 * 1024 * 1024);            // 64 KB
    float* sdst = ssrc + 8 * 2048;                                            // 64 KB

    gat_prep<<<2304, 256, 0, stream>>>(adj, h, W, a, msk, wht, ssrc, sdst);
    gat_attn<<<512, 512, 0, stream>>>(msk, wht, ssrc, sdst, (float*)d_out);
}

// Round 12
// 77.119 us; speedup vs baseline: 1.6040x; 1.6040x over previous
//
#include <hip/hip_runtime.h>
#include <hip/hip_bf16.h>

typedef __bf16 bf16x8 __attribute__((ext_vector_type(8)));
typedef __bf16 bf16x4 __attribute__((ext_vector_type(4)));
typedef float  f32x4  __attribute__((ext_vector_type(4)));
typedef float  flt4v  __attribute__((ext_vector_type(4)));
typedef int    int4v  __attribute__((ext_vector_type(4)));

#define ALPHA 0.2f
#define LOG2E 1.44269504089f
// B=8, N=2048, D=128. Inputs: h,W,a f32; adj int32. Output f32.
//
// Wh is stored in MFMA-B-fragment-native tiled order:
//   T[b][jt(32)][kk(2)][ct(8)][lane(64)][u(8)]  (bf16, 512 KB/batch)
// where element = Wh[j = jt*64 + kk*32 + (lane>>4)*8 + u][col = ct*16 + (lane&15)].
// attn's B-frag load is then T + const + lane*16 -> perfectly coalesced 1KB/instr.

// spread 16 bits so bit m -> bit 4m (bit-plane -> chunk-word transpose)
__device__ __forceinline__ unsigned long long spread4(unsigned long long x) {
    x &= 0xFFFFull;
    x = (x | (x << 24)) & 0x000000FF000000FFull;
    x = (x | (x << 12)) & 0x000F000F000F000Full;
    x = (x | (x << 6))  & 0x0303030303030303ull;
    x = (x | (x << 3))  & 0x1111111111111111ull;
    return x;
}

// Fused prep: blocks [0,2048) pack adj -> bitmask; blocks [2048,2304) compute
// Wh = bf16(h)@bf16(W) via MFMA + f32 scores (pre-scaled by log2e for exp2).
__global__ __launch_bounds__(256) void gat_prep(
    const int*   __restrict__ adj,           // [8*2048*2048]
    const float* __restrict__ h,             // [8][2048][128] f32
    const float* __restrict__ W,             // [128][128] f32
    const float* __restrict__ a,             // [256] f32
    unsigned long long* __restrict__ msk,    // [8*2048*32]
    __bf16* __restrict__ T,                  // [8][262144] bf16 tiled Wh
    float* __restrict__ ssrc,                // [8*2048] (x log2e)
    float* __restrict__ sdst)                // [8*2048] (x log2e)
{
    __shared__ __bf16 Wt[128][136];
    __shared__ float wvs[128], wvd[128];
    const int tid = threadIdx.x;

    if (blockIdx.x < 2048) {
        const int lane = tid & 63;
        const int wid  = (blockIdx.x * 256 + tid) >> 6;   // 8192 waves
        const int g0   = wid * 16;
        #pragma unroll 4
        for (int it = 0; it < 16; ++it) {
            const int g = g0 + it;
            int4v v = *reinterpret_cast<const int4v*>(adj + (size_t)g * 256 + lane * 4);
            unsigned long long b0 = __ballot(v[0] != 0);
            unsigned long long b1 = __ballot(v[1] != 0);
            unsigned long long b2 = __ballot(v[2] != 0);
            unsigned long long b3 = __ballot(v[3] != 0);
            if (lane < 4) {
                const int k = lane;
                unsigned long long w =  spread4(b0 >> (16 * k))
                                     | (spread4(b1 >> (16 * k)) << 1)
                                     | (spread4(b2 >> (16 * k)) << 2)
                                     | (spread4(b3 >> (16 * k)) << 3);
                msk[(size_t)g * 4 + k] = w;
            }
        }
        return;
    }

    // ---- wh part ----
    const int bidw = blockIdx.x - 2048;      // 0..255
    if (tid < 128) {
        float s0 = 0.f, s1 = 0.f;
        const float* wr = W + tid * 128;
        #pragma unroll 4
        for (int e = 0; e < 128; ++e) {
            float w = wr[e];
            s0 += w * a[e];
            s1 += w * a[128 + e];
        }
        wvs[tid] = s0; wvd[tid] = s1;
    }
    #pragma unroll
    for (int it = 0; it < 8; ++it) {
        int o = (it * 256 + tid) * 8;
        flt4v v0 = *reinterpret_cast<const flt4v*>(W + o);
        flt4v v1 = *reinterpret_cast<const flt4v*>(W + o + 4);
        int d = o >> 7, e = o & 127;
        #pragma unroll
        for (int j = 0; j < 4; ++j) {
            Wt[e + j][d]     = (__bf16)v0[j];
            Wt[e + 4 + j][d] = (__bf16)v1[j];
        }
    }
    __syncthreads();
    const int wave = tid >> 6, lane = tid & 63;
    const int lr = lane & 15, lg = lane >> 4;
    const int row0 = bidw * 64 + wave * 16;
    f32x4 acc[8];
    #pragma unroll
    for (int ct = 0; ct < 8; ++ct) acc[ct] = (f32x4){0.f, 0.f, 0.f, 0.f};
    #pragma unroll
    for (int kk = 0; kk < 4; ++kk) {
        const float* hp = h + (size_t)(row0 + lr) * 128 + kk * 32 + lg * 8;
        flt4v h0 = *reinterpret_cast<const flt4v*>(hp);
        flt4v h1 = *reinterpret_cast<const flt4v*>(hp + 4);
        bf16x8 af;
        #pragma unroll
        for (int j = 0; j < 4; ++j) { af[j] = (__bf16)h0[j]; af[4 + j] = (__bf16)h1[j]; }
        #pragma unroll
        for (int ct = 0; ct < 8; ++ct) {
            bf16x8 bf_ = *reinterpret_cast<const bf16x8*>(&Wt[ct * 16 + lr][kk * 32 + lg * 8]);
            acc[ct] = __builtin_amdgcn_mfma_f32_16x16x32_bf16(af, bf_, acc[ct], 0, 0, 0);
        }
    }
    // D layout: Wh row j = n0 + lg*4 + q, col = ct*16 + lr.
    // Store into tiled T: offset = ((jt*2+kk)*8+ct)*512 + lgp*128 + lr*8 + u0, 4 consecutive u.
    const int b  = row0 >> 11;
    const int n0 = row0 & 2047;
    __bf16* tb = T + (size_t)b * 262144;
    const int j0t = n0 + lg * 4;             // this thread's first j (q=0)
    const int jt  = j0t >> 6;
    const int kk2 = (j0t >> 5) & 1;
    const int lgp = (j0t >> 3) & 3;
    const int u0  = j0t & 7;                 // 0 or 4
    #pragma unroll
    for (int ct = 0; ct < 8; ++ct) {
        bf16x4 v;
        #pragma unroll
        for (int q = 0; q < 4; ++q) v[q] = (__bf16)acc[ct][q];
        *reinterpret_cast<bf16x4*>(tb + ((jt * 2 + kk2) * 8 + ct) * 512 + lgp * 128 + lr * 8 + u0) = v;
    }
    const float* hrow = h + (size_t)(row0 + lr) * 128 + lg * 32;
    float s0 = 0.f, s1 = 0.f;
    #pragma unroll
    for (int u = 0; u < 32; u += 4) {
        flt4v hv = *reinterpret_cast<const flt4v*>(hrow + u);
        #pragma unroll
        for (int q = 0; q < 4; ++q) {
            float x = hv[q];
            s0 += x * wvs[lg * 32 + u + q];
            s1 += x * wvd[lg * 32 + u + q];
        }
    }
    s0 += __shfl_xor(s0, 16, 64); s0 += __shfl_xor(s0, 32, 64);
    s1 += __shfl_xor(s1, 16, 64); s1 += __shfl_xor(s1, 32, 64);
    if (lg == 0) {
        ssrc[row0 + lr] = s0 * LOG2E;
        sdst[row0 + lr] = s1 * LOG2E;
    }
}

// Kernel C: fused masked-softmax attention + PV. Output f32.
// Grid: 512 blocks; bid&7 = batch (XCD pinning), bid>>3 = 32-row tile.
// Block: 512 thr = 8 waves: wave>>2 = row-group (16 rows), wave&3 = j-slice.
// B-frags from tiled T: coalesced 1KB/instruction streaming loads.
__global__ __launch_bounds__(512) void gat_attn(
    const unsigned long long* __restrict__ msk, // [8*2048][32] u64 bitmask
    const __bf16* __restrict__ T,               // [8][262144] bf16 tiled Wh
    const float* __restrict__ ssrc,             // pre-scaled by log2e
    const float* __restrict__ sdst,             // pre-scaled by log2e
    float* __restrict__ out)                    // [8][2048][128] f32
{
    __shared__ float accsh[2][16][136];
    __shared__ float lsh[2][16];
    const int tid = threadIdx.x, wave = tid >> 6, lane = tid & 63;
    const int lr = lane & 15, lg = lane >> 4;
    const int g = wave >> 2, slot = wave & 3;
    const int b  = blockIdx.x & 7;              // XCD pinning
    const int i0 = (blockIdx.x >> 3) << 5;      // 32-row tile base
    const int row = i0 + g * 16 + lr;
    const float si = ssrc[b * 2048 + row];
    const unsigned long long* mrow = msk + (size_t)(b * 2048 + row) * 32;
    const float* sd = sdst + b * 2048;
    const __bf16* tb = T + (size_t)b * 262144;

    f32x4 acc[8];
    #pragma unroll
    for (int ct = 0; ct < 8; ++ct) acc[ct] = (f32x4){0.f, 0.f, 0.f, 0.f};
    float lpart = 0.f;

    #pragma unroll 2
    for (int t = 0; t < 8; ++t) {
        const int jt = slot + 4 * t;
        const int j0 = jt * 64;
        const unsigned long long mw = mrow[jt];
        bf16x8 pf[2];
        #pragma unroll
        for (int kk = 0; kk < 2; ++kk) {
            const int jb = j0 + kk * 32 + lg * 8;
            const unsigned int m8 = (unsigned int)(mw >> (kk * 32 + lg * 8)) & 0xffu;
            #pragma unroll
            for (int v = 0; v < 2; ++v) {
                flt4v sv = *reinterpret_cast<const flt4v*>(sd + jb + v * 4);
                #pragma unroll
                for (int u = 0; u < 4; ++u) {
                    float e = si + sv[u];
                    e = fmaxf(e, ALPHA * e);        // leaky_relu (scaled domain, c>0 commutes)
                    float p = exp2f(e);
                    p = (m8 & (1u << (v * 4 + u))) ? p : 0.f;
                    __bf16 pb = (__bf16)p;
                    lpart += (float)pb;             // denom matches bf16 numerator
                    pf[kk][v * 4 + u] = pb;
                }
            }
        }
        #pragma unroll
        for (int kk = 0; kk < 2; ++kk) {
            const __bf16* tk = tb + ((jt * 2 + kk) * 8) * 512 + lane * 8;
            #pragma unroll
            for (int ct = 0; ct < 8; ++ct) {
                bf16x8 bf_ = *reinterpret_cast<const bf16x8*>(tk + ct * 512);
                acc[ct] = __builtin_amdgcn_mfma_f32_16x16x32_bf16(pf[kk], bf_, acc[ct], 0, 0, 0);
            }
        }
    }
    lpart += __shfl_xor(lpart, 16, 64);
    lpart += __shfl_xor(lpart, 32, 64);

    #pragma unroll
    for (int s = 0; s < 4; ++s) {
        if (slot == s) {
            if (s == 0) {
                #pragma unroll
                for (int ct = 0; ct < 8; ++ct)
                    #pragma unroll
                    for (int q = 0; q < 4; ++q)
                        accsh[g][lg * 4 + q][ct * 16 + lr] = acc[ct][q];
                if (lane < 16) lsh[g][lr] = lpart;
            } else {
                #pragma unroll
                for (int ct = 0; ct < 8; ++ct)
                    #pragma unroll
                    for (int q = 0; q < 4; ++q)
                        accsh[g][lg * 4 + q][ct * 16 + lr] += acc[ct][q];
                if (lane < 16) lsh[g][lr] += lpart;
            }
        }
        __syncthreads();
    }

    const int r  = tid >> 4;
    const int c0 = (tid & 15) * 8;
    const int rg = r >> 4, rr = r & 15;
    const float l = lsh[rg][rr];
    float* ob = out + ((size_t)b * 2048 + i0 + r) * 128 + c0;
    flt4v o0, o1;
    #pragma unroll
    for (int u = 0; u < 4; ++u) {
        o0[u] = accsh[rg][rr][c0 + u] / l;
        o1[u] = accsh[rg][rr][c0 + 4 + u] / l;
    }
    *reinterpret_cast<flt4v*>(ob)     = o0;
    *reinterpret_cast<flt4v*>(ob + 4) = o1;
}

extern "C" void kernel_launch(void* const* d_in, const int* in_sizes, int n_in,
                              void* d_out, int out_size, void* d_ws, size_t ws_size,
                              hipStream_t stream)
{
    const float* h = nullptr; const int* adj = nullptr;
    const float* W = nullptr; const float* a = nullptr;
    for (int i = 0; i < n_in; ++i) {
        switch (in_sizes[i]) {
            case 2097152:  h   = (const float*)d_in[i]; break;  // 8*2048*128
            case 33554432: adj = (const int*)d_in[i];   break;  // 8*2048*2048
            case 16384:    W   = (const float*)d_in[i]; break;  // 128*128
            case 256:      a   = (const float*)d_in[i]; break;  // 2*128
        }
    }
    if (!h || !adj || !W || !a) {
        h   = (const float*)d_in[0];
        adj = (const int*)d_in[1];
        W   = (const float*)d_in[2];
        a   = (const float*)d_in[3];
    }

    __bf16* T = (__bf16*)d_ws;                                                // 4 MB tiled Wh
    unsigned long long* msk = (unsigned long long*)((char*)d_ws + (size_t)4*1024*1024); // 4 MB
    float* ssrc = (float*)((char*)d_ws + (size_t)8 * 1024 * 1024);            // 64 KB
    float* sdst = ssrc + 8 * 2048;                                            // 64 KB

    gat_prep<<<2304, 256, 0, stream>>>(adj, h, W, a, msk, T, ssrc, sdst);
    gat_attn<<<512, 512, 0, stream>>>(msk, T, ssrc, sdst, (float*)d_out);
}